// Round 1
// baseline (1283.900 us; speedup 1.0000x reference)
//
#include <hip/hip_runtime.h>
#include <math.h>

#define NBATCH 8
#define NPOINT 32768
#define NFEAT 256
#define NPROP 256
#define NSAMP 16
#define KIN 259
#define HDIM 128
#define ODIM 97

// ---- exact-rounding helpers: block fma contraction on boundary-critical math
__device__ __forceinline__ float addrn(float a, float b) {
  float r; asm("v_add_f32 %0, %1, %2" : "=v"(r) : "v"(a), "v"(b)); return r;
}
__device__ __forceinline__ float subrn(float a, float b) {
  float r; asm("v_sub_f32 %0, %1, %2" : "=v"(r) : "v"(a), "v"(b)); return r;
}

// ---------------- FPS: one block per batch, dist in LDS, xyz in registers ---
__global__ __launch_bounds__(512)
void fps_kernel(const float* __restrict__ xyz, int* __restrict__ fpsi,
                float* __restrict__ cxyz) {
  __shared__ __align__(16) float dist[NPOINT];   // 128 KB
  __shared__ float rv[8];
  __shared__ int ri[8];
  __shared__ int bc;
  const int b = blockIdx.x;
  const int t = threadIdx.x;
  const float* __restrict__ Xp = xyz + (size_t)b * NPOINT * 3;
  float px[64], py[64], pz[64];
#pragma unroll
  for (int q = 0; q < 16; ++q) {
#pragma unroll
    for (int u = 0; u < 4; ++u) {
      const int i = q * 2048 + t * 4 + u;
      px[q*4+u] = Xp[3*i+0];
      py[q*4+u] = Xp[3*i+1];
      pz[q*4+u] = Xp[3*i+2];
    }
    *(float4*)&dist[q*2048 + t*4] = make_float4(1e10f, 1e10f, 1e10f, 1e10f);
  }
  __syncthreads();
  int last = 0;
  for (int step = 0; step < NPROP; ++step) {
    const float qx = Xp[3*last+0];
    const float qy = Xp[3*last+1];
    const float qz = Xp[3*last+2];
    if (t == 0) {
      fpsi[b*NPROP + step] = last;
      cxyz[(b*NPROP+step)*3+0] = qx;
      cxyz[(b*NPROP+step)*3+1] = qy;
      cxyz[(b*NPROP+step)*3+2] = qz;
    }
    float bv = -1.0f; int bi = 0;
#pragma unroll
    for (int q = 0; q < 16; ++q) {
      float4 dv = *(float4*)&dist[q*2048 + t*4];
      float* dp = (float*)&dv;
#pragma unroll
      for (int u = 0; u < 4; ++u) {
        const int j = q*4+u;
        const float dx = px[j]-qx, dy = py[j]-qy, dz = pz[j]-qz;
        const float d = addrn(addrn(dx*dx, dy*dy), dz*dz);  // ((dx2+dy2)+dz2), no fma
        const float nd = fminf(dp[u], d);
        dp[u] = nd;
        if (nd > bv) { bv = nd; bi = q*2048 + t*4 + u; }  // strict >: first-max (smallest i)
      }
      *(float4*)&dist[q*2048 + t*4] = dv;
    }
    // wave butterfly reduce, lexicographic (max value, min index)
#pragma unroll
    for (int m = 1; m < 64; m <<= 1) {
      const float ov = __shfl_xor(bv, m);
      const int   oi = __shfl_xor(bi, m);
      if (ov > bv || (ov == bv && oi < bi)) { bv = ov; bi = oi; }
    }
    if ((t & 63) == 0) { rv[t >> 6] = bv; ri[t >> 6] = bi; }
    __syncthreads();
    if (t < 64) {
      float fv = (t < 8) ? rv[t] : -2.0f;
      int   fi = (t < 8) ? ri[t] : 0x7fffffff;
#pragma unroll
      for (int m = 1; m < 8; m <<= 1) {
        const float ov = __shfl_xor(fv, m);
        const int   oi = __shfl_xor(fi, m);
        if (ov > fv || (ov == fv && oi < fi)) { fv = ov; fi = oi; }
      }
      if (t == 0) bc = fi;
    }
    __syncthreads();
    last = bc;
  }
}

// ---------------- Ball query: one wave per (b,p); first-16-indices scan -----
__global__ __launch_bounds__(512)
void ballq_kernel(const float* __restrict__ xyz, const float* __restrict__ cxyz,
                  int* __restrict__ idx) {
  const int gw = (blockIdx.x * 512 + threadIdx.x) >> 6;   // 0..2047
  const int lane = threadIdx.x & 63;
  const int b = gw >> 8;
  const float* __restrict__ Xp = xyz + (size_t)b * NPOINT * 3;
  const float cx = cxyz[gw*3+0], cy = cxyz[gw*3+1], cz = cxyz[gw*3+2];
  const float a = addrn(addrn(cx*cx, cy*cy), cz*cz);
  const float R2 = (float)(0.3 * 0.3);
  int* __restrict__ out = idx + gw * NSAMP;
  int cnt = 0, first = -1;
  for (int base = 0; base < NPOINT; base += 64) {
    const int i = base + lane;
    const float x = Xp[3*i+0], y = Xp[3*i+1], z = Xp[3*i+2];
    const float bb2 = addrn(addrn(x*x, y*y), z*z);
    const float cc  = addrn(addrn(cx*x, cy*y), cz*z);
    const float d2  = subrn(addrn(a, bb2), 2.0f*cc);      // (a+b) - 2c, no fma
    const bool isin = d2 < R2;
    const unsigned long long m = __ballot(isin);
    if (m) {
      if (first < 0) first = base + (int)__builtin_ctzll(m);
      if (isin) {
        const int pos = cnt + (int)__builtin_popcountll(m & ((1ull << lane) - 1ull));
        if (pos < NSAMP) out[pos] = i;
      }
      cnt += (int)__builtin_popcountll(m);
      if (cnt >= NSAMP) break;
    }
  }
  if (lane < NSAMP && lane >= cnt) out[lane] = first;
}

// ---------------- Layer0: gather + (259->128) + BN + ReLU, persistent -------
__global__ __launch_bounds__(256)
void mlp0_kernel(const float* __restrict__ xyz, const float* __restrict__ feat,
                 const float* __restrict__ cxyz, const int* __restrict__ idx,
                 const float* __restrict__ W, const float* __restrict__ bias_,
                 const float* __restrict__ gam_, const float* __restrict__ bet_,
                 float* __restrict__ h0) {
  __shared__ __align__(16) float w[KIN*132];    // 136.8 KB
  __shared__ __align__(16) float xs[16*264];    // 16.9 KB
  __shared__ int ids[16];
  const int t = threadIdx.x;
  for (int i = t; i < KIN*HDIM; i += 256) {
    const int k = i >> 7, c = i & 127;
    w[k*132 + c] = W[i];
  }
  const int r  = t >> 4;
  const int c8 = (t & 15) * 8;
  float bs[8], gm[8], bt[8];
#pragma unroll
  for (int j = 0; j < 8; ++j) { bs[j] = bias_[c8+j]; gm[j] = gam_[c8+j]; bt[j] = bet_[c8+j]; }
  const float bns = (float)(1.0 / sqrt(1.001));
  for (int gi = 0; gi < 8; ++gi) {
    const int g = blockIdx.x * 8 + gi;
    const int b = g >> 8;
    __syncthreads();
    if (t < 16) ids[t] = idx[g*16 + t];
    __syncthreads();
#pragma unroll
    for (int s = 0; s < 16; ++s)
      xs[s*264 + 3 + t] = feat[((size_t)b*NPOINT + ids[s])*NFEAT + t];
    if (t < 48) {
      const int s = t / 3, d = t - 3*(t/3);
      const float v = xyz[((size_t)b*NPOINT + ids[s])*3 + d];
      xs[s*264 + d] = (v - cxyz[g*3 + d]) / 0.3f;
    }
    __syncthreads();
    float acc[8];
#pragma unroll
    for (int j = 0; j < 8; ++j) acc[j] = bs[j];
    for (int k = 0; k < KIN; ++k) {
      const float xv = xs[r*264 + k];
      const float4 wa = *(const float4*)&w[k*132 + c8];
      const float4 wb = *(const float4*)&w[k*132 + c8 + 4];
      acc[0] += xv*wa.x; acc[1] += xv*wa.y; acc[2] += xv*wa.z; acc[3] += xv*wa.w;
      acc[4] += xv*wb.x; acc[5] += xv*wb.y; acc[6] += xv*wb.z; acc[7] += xv*wb.w;
    }
    float ov[8];
#pragma unroll
    for (int j = 0; j < 8; ++j) ov[j] = fmaxf(gm[j]*(acc[j]*bns)+bt[j], 0.0f);
    float* dst = &h0[((size_t)g*16 + r)*HDIM + c8];
    *(float4*)&dst[0] = make_float4(ov[0],ov[1],ov[2],ov[3]);
    *(float4*)&dst[4] = make_float4(ov[4],ov[5],ov[6],ov[7]);
  }
}

// ---------------- Layers 1+2 + maxpool over S, persistent -------------------
__global__ __launch_bounds__(256)
void mlp12_kernel(const float* __restrict__ h0,
                  const float* __restrict__ W1, const float* __restrict__ b1,
                  const float* __restrict__ g1, const float* __restrict__ e1,
                  const float* __restrict__ W2, const float* __restrict__ b2,
                  const float* __restrict__ g2, const float* __restrict__ e2,
                  float* __restrict__ feats) {
  __shared__ __align__(16) float w1[HDIM*132];
  __shared__ __align__(16) float w2[HDIM*132];
  __shared__ __align__(16) float xs[16*132];
  __shared__ __align__(16) float ys[16*132];
  const int t = threadIdx.x;
  for (int i = t; i < HDIM*HDIM; i += 256) {
    const int k = i >> 7, c = i & 127;
    w1[k*132+c] = W1[i];
    w2[k*132+c] = W2[i];
  }
  const int r  = t >> 4;
  const int c8 = (t & 15) * 8;
  float bs1[8], gm1[8], bt1[8], bs2[8], gm2[8], bt2[8];
#pragma unroll
  for (int j = 0; j < 8; ++j) {
    bs1[j]=b1[c8+j]; gm1[j]=g1[c8+j]; bt1[j]=e1[c8+j];
    bs2[j]=b2[c8+j]; gm2[j]=g2[c8+j]; bt2[j]=e2[c8+j];
  }
  const float bns = (float)(1.0 / sqrt(1.001));
  for (int gi = 0; gi < 8; ++gi) {
    const int g = blockIdx.x * 8 + gi;
    __syncthreads();
    for (int i = t; i < 16*HDIM; i += 256) {
      const int s = i >> 7, k = i & 127;
      xs[s*132+k] = h0[((size_t)g*16 + s)*HDIM + k];
    }
    __syncthreads();
    float acc[8];
#pragma unroll
    for (int j = 0; j < 8; ++j) acc[j] = bs1[j];
#pragma unroll 4
    for (int k = 0; k < HDIM; ++k) {
      const float xv = xs[r*132 + k];
      const float4 wa = *(const float4*)&w1[k*132 + c8];
      const float4 wb = *(const float4*)&w1[k*132 + c8 + 4];
      acc[0]+=xv*wa.x; acc[1]+=xv*wa.y; acc[2]+=xv*wa.z; acc[3]+=xv*wa.w;
      acc[4]+=xv*wb.x; acc[5]+=xv*wb.y; acc[6]+=xv*wb.z; acc[7]+=xv*wb.w;
    }
    {
      float ov[8];
#pragma unroll
      for (int j = 0; j < 8; ++j) ov[j] = fmaxf(gm1[j]*(acc[j]*bns)+bt1[j], 0.0f);
      *(float4*)&ys[r*132 + c8]     = make_float4(ov[0],ov[1],ov[2],ov[3]);
      *(float4*)&ys[r*132 + c8 + 4] = make_float4(ov[4],ov[5],ov[6],ov[7]);
    }
    __syncthreads();
#pragma unroll
    for (int j = 0; j < 8; ++j) acc[j] = bs2[j];
#pragma unroll 4
    for (int k = 0; k < HDIM; ++k) {
      const float xv = ys[r*132 + k];
      const float4 wa = *(const float4*)&w2[k*132 + c8];
      const float4 wb = *(const float4*)&w2[k*132 + c8 + 4];
      acc[0]+=xv*wa.x; acc[1]+=xv*wa.y; acc[2]+=xv*wa.z; acc[3]+=xv*wa.w;
      acc[4]+=xv*wb.x; acc[5]+=xv*wb.y; acc[6]+=xv*wb.z; acc[7]+=xv*wb.w;
    }
    {
      float ov[8];
#pragma unroll
      for (int j = 0; j < 8; ++j) ov[j] = fmaxf(gm2[j]*(acc[j]*bns)+bt2[j], 0.0f);
      *(float4*)&xs[r*132 + c8]     = make_float4(ov[0],ov[1],ov[2],ov[3]);  // xs reused as pool buf
      *(float4*)&xs[r*132 + c8 + 4] = make_float4(ov[4],ov[5],ov[6],ov[7]);
    }
    __syncthreads();
#pragma unroll
    for (int hh = 8; hh >= 1; hh >>= 1) {
      if (r < hh) {
#pragma unroll
        for (int j = 0; j < 8; ++j)
          xs[r*132 + c8 + j] = fmaxf(xs[r*132 + c8 + j], xs[(r+hh)*132 + c8 + j]);
      }
      __syncthreads();
    }
    if (r == 0) {
      *(float4*)&feats[(size_t)g*HDIM + c8]     = *(float4*)&xs[c8];
      *(float4*)&feats[(size_t)g*HDIM + c8 + 4] = *(float4*)&xs[c8+4];
    }
  }
}

// ---------------- Head layers 1/2 (128->128, BN+ReLU), 16 rows/block --------
__global__ __launch_bounds__(256)
void head_kernel(const float* __restrict__ in_, const float* __restrict__ W,
                 const float* __restrict__ b_, const float* __restrict__ g_,
                 const float* __restrict__ e_, float* __restrict__ out_) {
  __shared__ __align__(16) float w[HDIM*132];
  __shared__ __align__(16) float xs[16*132];
  const int t = threadIdx.x;
  for (int i = t; i < HDIM*HDIM; i += 256) {
    const int k = i >> 7, c = i & 127;
    w[k*132+c] = W[i];
  }
  const int row0 = blockIdx.x * 16;
  for (int i = t; i < 16*HDIM; i += 256) {
    const int s = i >> 7, k = i & 127;
    xs[s*132+k] = in_[((size_t)row0 + s)*HDIM + k];
  }
  const int r  = t >> 4;
  const int c8 = (t & 15) * 8;
  float bs[8], gm[8], bt[8];
#pragma unroll
  for (int j = 0; j < 8; ++j) { bs[j]=b_[c8+j]; gm[j]=g_[c8+j]; bt[j]=e_[c8+j]; }
  const float bns = (float)(1.0 / sqrt(1.001));
  __syncthreads();
  float acc[8];
#pragma unroll
  for (int j = 0; j < 8; ++j) acc[j] = bs[j];
#pragma unroll 4
  for (int k = 0; k < HDIM; ++k) {
    const float xv = xs[r*132 + k];
    const float4 wa = *(const float4*)&w[k*132 + c8];
    const float4 wb = *(const float4*)&w[k*132 + c8 + 4];
    acc[0]+=xv*wa.x; acc[1]+=xv*wa.y; acc[2]+=xv*wa.z; acc[3]+=xv*wa.w;
    acc[4]+=xv*wb.x; acc[5]+=xv*wb.y; acc[6]+=xv*wb.z; acc[7]+=xv*wb.w;
  }
  float ov[8];
#pragma unroll
  for (int j = 0; j < 8; ++j) ov[j] = fmaxf(gm[j]*(acc[j]*bns)+bt[j], 0.0f);
  float* dst = &out_[((size_t)row0 + r)*HDIM + c8];
  *(float4*)&dst[0] = make_float4(ov[0],ov[1],ov[2],ov[3]);
  *(float4*)&dst[4] = make_float4(ov[4],ov[5],ov[6],ov[7]);
}

// ---------------- Head3 (128->97) + output assembly -------------------------
__global__ __launch_bounds__(128)
void head3_kernel(const float* __restrict__ net2, const float* __restrict__ W3,
                  const float* __restrict__ b3, const float* __restrict__ cxyz,
                  float* __restrict__ out) {
  __shared__ float x[HDIM];
  const int g = blockIdx.x;   // 0..2047
  const int t = threadIdx.x;
  x[t] = net2[(size_t)g*HDIM + t];
  __syncthreads();
  if (t >= ODIM) return;
  float acc = b3[t];
#pragma unroll 4
  for (int k = 0; k < HDIM; ++k) acc += x[k] * W3[k*ODIM + t];
  const int OBJ=0, CEN=4096, HSo=10240, HRN=12288, HRo=14336,
            SSo=16384, SRN=53248, SRo=163840, SEM=274432;
  if (t < 2)       out[OBJ + g*2 + t] = acc;
  else if (t < 5)  out[CEN + g*3 + (t-2)] = acc + cxyz[g*3 + (t-2)];
  else if (t == 5) out[HSo + g] = acc;
  else if (t == 6) { out[HRN + g] = acc; out[HRo + g] = acc * (float)M_PI; }
  else if (t < 25) out[SSo + g*18 + (t-7)] = acc;
  else if (t < 79) {
    const int m2 = t - 25;
    out[SRN + g*54 + m2] = acc;
    out[SRo + g*54 + m2] = acc * ((float)(m2 % 5 + 1) * 0.2f);
  }
  else             out[SEM + g*18 + (t-79)] = acc;
}

extern "C" void kernel_launch(void* const* d_in, const int* in_sizes, int n_in,
                              void* d_out, int out_size, void* d_ws, size_t ws_size,
                              hipStream_t stream) {
  (void)in_sizes; (void)n_in; (void)out_size; (void)ws_size;
  const float* xyz  = (const float*)d_in[0];
  const float* feat = (const float*)d_in[1];
  const float* mw0 = (const float*)d_in[2];
  const float* mb0 = (const float*)d_in[3];
  const float* mg0 = (const float*)d_in[4];
  const float* me0 = (const float*)d_in[5];
  const float* mw1 = (const float*)d_in[6];
  const float* mb1 = (const float*)d_in[7];
  const float* mg1 = (const float*)d_in[8];
  const float* me1 = (const float*)d_in[9];
  const float* mw2 = (const float*)d_in[10];
  const float* mb2 = (const float*)d_in[11];
  const float* mg2 = (const float*)d_in[12];
  const float* me2 = (const float*)d_in[13];
  const float* hw1 = (const float*)d_in[14];
  const float* hb1 = (const float*)d_in[15];
  const float* hg1 = (const float*)d_in[16];
  const float* he1 = (const float*)d_in[17];
  const float* hw2 = (const float*)d_in[18];
  const float* hb2 = (const float*)d_in[19];
  const float* hg2 = (const float*)d_in[20];
  const float* he2 = (const float*)d_in[21];
  const float* hw3 = (const float*)d_in[22];
  const float* hb3 = (const float*)d_in[23];
  float* out = (float*)d_out;
  char* ws = (char*)d_ws;
  // ws layout (bytes): fpsi[2048 i32] @0; cxyz[6144 f32] @8192; idx[32768 i32] @32768;
  // h0[32768*128 f32] @163840; feats[2048*128] @16941056; net1 @17989632; net2 @19038208
  int*   fpsi = (int*)(ws + 0);
  float* cxyz = (float*)(ws + 8192);
  int*   idx  = (int*)(ws + 32768);
  float* h0   = (float*)(ws + 163840);
  float* fts  = (float*)(ws + 16941056);
  float* net1 = (float*)(ws + 17989632);
  float* net2 = (float*)(ws + 19038208);

  fps_kernel<<<NBATCH, 512, 0, stream>>>(xyz, fpsi, cxyz);
  ballq_kernel<<<256, 512, 0, stream>>>(xyz, cxyz, idx);
  mlp0_kernel<<<256, 256, 0, stream>>>(xyz, feat, cxyz, idx, mw0, mb0, mg0, me0, h0);
  mlp12_kernel<<<256, 256, 0, stream>>>(h0, mw1, mb1, mg1, me1, mw2, mb2, mg2, me2, fts);
  head_kernel<<<128, 256, 0, stream>>>(fts, hw1, hb1, hg1, he1, net1);
  head_kernel<<<128, 256, 0, stream>>>(net1, hw2, hb2, hg2, he2, net2);
  head3_kernel<<<2048, 128, 0, stream>>>(net2, hw3, hb3, cxyz, out);
}